// Round 10
// baseline (113.024 us; speedup 1.0000x reference)
//
#include <hip/hip_runtime.h>
#include <hip/hip_bf16.h>

#define BSZ 4
#define NN 512
#define INDIM 256
#define H1 128
#define EMBD 64

#define PRED_OFF  (BSZ*NN*NN)                   // 1048576 elements
#define PRED_PER_B (NN*(NN-1)*2)                // 523264
#define EMB_OFF   (PRED_OFF + BSZ*PRED_PER_B)   // 3141632

typedef __attribute__((ext_vector_type(8))) short bf16x8;
typedef __attribute__((ext_vector_type(4))) float f32x4;

static __device__ __forceinline__ short bfs(float x) {
  return (short)__builtin_bit_cast(unsigned short, __float2bfloat16(x));
}
static __device__ __forceinline__ bf16x8 pack8(float4 a, float4 b) {
  bf16x8 r;
  r[0] = bfs(a.x); r[1] = bfs(a.y); r[2] = bfs(a.z); r[3] = bfs(a.w);
  r[4] = bfs(b.x); r[5] = bfs(b.y); r[6] = bfs(b.z); r[7] = bfs(b.w);
  return r;
}

// Kernel 1: node MLP -> emb (f32 into d_out) + optional bf16 mirror in ws.
// 4-way partial accumulators + step-4 unroll: 8 independent FMA chains in
// fc1 (was 2 serial 256-chains), 4 loads in flight.
template<bool WS>
__global__ __launch_bounds__(256) void k1_embed(
    const float* __restrict__ nf, const float* __restrict__ fc1w,
    const float* __restrict__ fc1b, const float* __restrict__ fc2w,
    const float* __restrict__ fc2b, float* __restrict__ out,
    unsigned short* __restrict__ ebf)
{
  __shared__ float nfs[4][INDIM];
  __shared__ float hs[4][H1];
  const int t = threadIdx.x;
  const int nb = blockIdx.x * 4;

  {
    const int nd = t >> 6, off = (t & 63) * 4;
    *reinterpret_cast<float4*>(&nfs[nd][off]) =
        *reinterpret_cast<const float4*>(nf + (size_t)(nb + nd) * INDIM + off);
  }
  __syncthreads();
  {
    const int c = t & 127, grp = t >> 7;
    const float* __restrict__ wcol = fc1w + c;
    const float* __restrict__ x0 = nfs[grp];
    const float* __restrict__ x1 = nfs[grp + 2];
    float p00 = 0.f, p01 = 0.f, p02 = 0.f, p03 = 0.f;
    float p10 = 0.f, p11 = 0.f, p12 = 0.f, p13 = 0.f;
#pragma unroll 2
    for (int f = 0; f < INDIM; f += 4) {
      const float w0 = wcol[(f + 0) * H1];
      const float w1 = wcol[(f + 1) * H1];
      const float w2 = wcol[(f + 2) * H1];
      const float w3 = wcol[(f + 3) * H1];
      p00 = fmaf(x0[f + 0], w0, p00);
      p01 = fmaf(x0[f + 1], w1, p01);
      p02 = fmaf(x0[f + 2], w2, p02);
      p03 = fmaf(x0[f + 3], w3, p03);
      p10 = fmaf(x1[f + 0], w0, p10);
      p11 = fmaf(x1[f + 1], w1, p11);
      p12 = fmaf(x1[f + 2], w2, p12);
      p13 = fmaf(x1[f + 3], w3, p13);
    }
    const float bb = fc1b[c];
    const float a0 = (p00 + p01) + (p02 + p03) + bb;
    const float a1 = (p10 + p11) + (p12 + p13) + bb;
    hs[grp][c]     = a0 > 0.f ? a0 : 0.01f * a0;
    hs[grp + 2][c] = a1 > 0.f ? a1 : 0.01f * a1;
  }
  __syncthreads();
  {
    const int d = t & 63, nd = t >> 6;
    const float* __restrict__ wcol = fc2w + d;
    const float* __restrict__ hx = hs[nd];
    float p0 = 0.f, p1 = 0.f, p2 = 0.f, p3 = 0.f;
#pragma unroll 2
    for (int f = 0; f < H1; f += 4) {
      p0 = fmaf(hx[f + 0], wcol[(f + 0) * EMBD], p0);
      p1 = fmaf(hx[f + 1], wcol[(f + 1) * EMBD], p1);
      p2 = fmaf(hx[f + 2], wcol[(f + 2) * EMBD], p2);
      p3 = fmaf(hx[f + 3], wcol[(f + 3) * EMBD], p3);
    }
    const float acc = (p0 + p1) + (p2 + p3) + fc2b[d];
    const float e = acc > 0.f ? acc : 0.01f * acc;
    const size_t idx = (size_t)(nb + nd) * EMBD + d;
    out[EMB_OFF + idx] = e;
    if (WS) ebf[idx] = (unsigned short)bfs(e);
  }
}

// Kernel 2: ONE WAVE per block. Block owns (b, i, j-half of 256 j).
// D[h][j] = sum_d B'[d][h]*emb_j[d], B'[d][h] = emb_i[d]*w2[d][h] - w1[d][h],
// built directly into registers (no big LDS). eh = relu(D + a_i + e1_b);
// ldiff = sum_h eh*(e2w[h][1]-e2w[h][0]) + db; p1 = sigmoid(ldiff).
template<bool WS>
__global__ __launch_bounds__(64, 4) void k2_edges(
    const float* __restrict__ e1w, const float* __restrict__ e1b,
    const float* __restrict__ e2w, const float* __restrict__ e2b,
    float* __restrict__ out, const unsigned short* __restrict__ ebf)
{
  __shared__ float embi[64];
  __shared__ float ash[64];   // a_i[h] + e1_b[h]
  __shared__ float wds[64];   // e2w[h][1] - e2w[h][0]
  const int t = threadIdx.x;            // lane 0..63
  const int blk = blockIdx.x;
  const int b = blk >> 10;              // 1024 blocks per batch
  const int rr = blk & 1023;
  const int i = rr >> 1;
  const int jh = rr & 1;                // j-half: [jh*256, jh*256+256)
  const float* __restrict__ Ef = out + EMB_OFF;

  embi[t] = Ef[((size_t)(b * NN) + i) * EMBD + t];
  wds[t]  = e2w[2 * t + 1] - e2w[2 * t];
  __syncthreads();

  // a_i[h=t] = sum_d emb_i[d] * e1w[d][t]   (4 independent chains)
  {
    float q0 = 0.f, q1 = 0.f, q2 = 0.f, q3 = 0.f;
#pragma unroll 4
    for (int dd = 0; dd < EMBD; dd += 4) {
      q0 = fmaf(embi[dd + 0], e1w[(dd + 0) * 64 + t], q0);
      q1 = fmaf(embi[dd + 1], e1w[(dd + 1) * 64 + t], q1);
      q2 = fmaf(embi[dd + 2], e1w[(dd + 2) * 64 + t], q2);
      q3 = fmaf(embi[dd + 3], e1w[(dd + 3) * 64 + t], q3);
    }
    ash[t] = (q0 + q1) + (q2 + q3) + e1b[t];
  }
  __syncthreads();

  const int lg = t >> 4, ll = t & 15;

  // ci/wd as float4 per mt (h = mt*16 + lg*4 + r, contiguous in r)
  f32x4 ci[4], wd4[4];
#pragma unroll
  for (int mt = 0; mt < 4; ++mt) {
    ci[mt]  = *reinterpret_cast<const f32x4*>(&ash[mt * 16 + lg * 4]);
    wd4[mt] = *reinterpret_cast<const f32x4*>(&wds[mt * 16 + lg * 4]);
  }
  const float ldbias = e2b[1] - e2b[0];

  // A fragments built directly in registers:
  // afr[mt][ks][q] = B'[d = ks*32+lg*8+q][h = mt*16+ll]
  bf16x8 afr[4][2];
#pragma unroll
  for (int ks = 0; ks < 2; ++ks) {
    float e8[8];
    *reinterpret_cast<float4*>(&e8[0]) =
        *reinterpret_cast<const float4*>(&embi[ks * 32 + lg * 8]);
    *reinterpret_cast<float4*>(&e8[4]) =
        *reinterpret_cast<const float4*>(&embi[ks * 32 + lg * 8 + 4]);
#pragma unroll
    for (int mt = 0; mt < 4; ++mt) {
      const int h = mt * 16 + ll;
      bf16x8 a;
#pragma unroll
      for (int q = 0; q < 8; ++q) {
        const int d = ks * 32 + lg * 8 + q;
        a[q] = bfs(fmaf(e8[q], e1w[(64 + d) * 64 + h], -e1w[d * 64 + h]));
      }
      afr[mt][ks] = a;
    }
  }

  const size_t adj_base = ((size_t)(b * NN) + i) * NN;
  const size_t pred_base =
      (size_t)PRED_OFF + (size_t)b * PRED_PER_B + (size_t)i * (NN - 1) * 2;

  auto loadB = [&](int j0, bf16x8& o0, bf16x8& o1) {
    if (WS) {
      const unsigned short* p =
          ebf + ((size_t)(b * NN) + j0 + ll) * EMBD + lg * 8;
      o0 = *reinterpret_cast<const bf16x8*>(p);
      o1 = *reinterpret_cast<const bf16x8*>(p + 32);
    } else {
      const float* ef = Ef + ((size_t)(b * NN) + j0 + ll) * EMBD + lg * 8;
      const float4 fa = *reinterpret_cast<const float4*>(ef);
      const float4 fb = *reinterpret_cast<const float4*>(ef + 4);
      const float4 fc = *reinterpret_cast<const float4*>(ef + 32);
      const float4 fd = *reinterpret_cast<const float4*>(ef + 36);
      o0 = pack8(fa, fb);
      o1 = pack8(fc, fd);
    }
  };

  const int jbase = jh * 256;
  bf16x8 pb0, pb1;
  loadB(jbase, pb0, pb1);

#pragma unroll 2
  for (int nt = 0; nt < 16; ++nt) {
    const bf16x8 b0 = pb0, b1 = pb1;
    if (nt < 15) loadB(jbase + (nt + 1) * 16, pb0, pb1);

    f32x4 acc[4];
#pragma unroll
    for (int mt = 0; mt < 4; ++mt)
      acc[mt] = __builtin_amdgcn_mfma_f32_16x16x32_bf16(afr[mt][0], b0, ci[mt], 0, 0, 0);
#pragma unroll
    for (int mt = 0; mt < 4; ++mt)
      acc[mt] = __builtin_amdgcn_mfma_f32_16x16x32_bf16(afr[mt][1], b1, acc[mt], 0, 0, 0);

    float lp0 = 0.f, lp1 = 0.f, lp2 = 0.f, lp3 = 0.f;
#pragma unroll
    for (int mt = 0; mt < 4; ++mt) {
      lp0 = fmaf(fmaxf(acc[mt][0], 0.f), wd4[mt][0], lp0);
      lp1 = fmaf(fmaxf(acc[mt][1], 0.f), wd4[mt][1], lp1);
      lp2 = fmaf(fmaxf(acc[mt][2], 0.f), wd4[mt][2], lp2);
      lp3 = fmaf(fmaxf(acc[mt][3], 0.f), wd4[mt][3], lp3);
    }
    float ldp = (lp0 + lp1) + (lp2 + lp3);
    ldp += __shfl_xor(ldp, 16, 64);
    ldp += __shfl_xor(ldp, 32, 64);

    const float x = ldp + ldbias;
    const float e = __builtin_amdgcn_exp2f(x * -1.44269504f);
    const float p1 = __builtin_amdgcn_rcpf(1.f + e);
    const float p0 = e * p1;

    if (t < 32) {
      const int j = jbase + nt * 16 + ll;
      if (t < 16) {
        out[adj_base + j] = p1;
      } else if (j != i) {
        const int jj = j - (j > i ? 1 : 0);
        *reinterpret_cast<float2*>(out + pred_base + (size_t)jj * 2) =
            make_float2(p0, p1);
      }
    }
  }
}

extern "C" void kernel_launch(void* const* d_in, const int* in_sizes, int n_in,
                              void* d_out, int out_size, void* d_ws, size_t ws_size,
                              hipStream_t stream) {
  const float* nf   = (const float*)d_in[0];
  const float* fc1w = (const float*)d_in[1];
  const float* fc1b = (const float*)d_in[2];
  const float* fc2w = (const float*)d_in[3];
  const float* fc2b = (const float*)d_in[4];
  const float* e1w  = (const float*)d_in[5];
  const float* e1b  = (const float*)d_in[6];
  const float* e2w  = (const float*)d_in[7];
  const float* e2b  = (const float*)d_in[8];
  float* out = (float*)d_out;
  unsigned short* ebf = (unsigned short*)d_ws;
  const bool use_ws = ws_size >= (size_t)BSZ * NN * EMBD * sizeof(unsigned short);

  if (use_ws) {
    k1_embed<true><<<BSZ * NN / 4, 256, 0, stream>>>(nf, fc1w, fc1b, fc2w, fc2b, out, ebf);
    k2_edges<true><<<BSZ * NN * 2, 64, 0, stream>>>(e1w, e1b, e2w, e2b, out, ebf);
  } else {
    k1_embed<false><<<BSZ * NN / 4, 256, 0, stream>>>(nf, fc1w, fc1b, fc2w, fc2b, out, nullptr);
    k2_edges<false><<<BSZ * NN * 2, 64, 0, stream>>>(e1w, e1b, e2w, e2b, out, nullptr);
  }
}